// Round 3
// baseline (40.862 us; speedup 1.0000x reference)
//
#include <hip/hip_runtime.h>

// BinaryTreeShConv on MI355X (gfx950).
// out[b,v,i] = relu(bias[i] + sum_{p,c,rn} W[i,c,rn] * K[b,v,p,rn] * sig[b, idx[b,v,p], c])
// B=8 V=4096 P=32 C=32 RN=32 OUT=32, CRN=1024.
//
// R2: stage-A latency restructure.
//  - idx tile -> LDS once per block (coalesced), removes idx from gather chain
//  - ck loaded coalesced (f32x4, all 4 q prefetched at wave start), staged via
//    wave-private LDS tile (stride 36: b64 writes ~conflict-free, u16 column
//    reads conflict-free) for the MFMA B-fragment
//  - gathers pipelined 1 q ahead
// Stage B / reduction / epilogue / prep identical to R1 (passed twice).

typedef __attribute__((ext_vector_type(8))) short bf16x8;
typedef __attribute__((ext_vector_type(4))) short short4v;
typedef __attribute__((ext_vector_type(16))) float f32x16;
typedef __attribute__((ext_vector_type(4))) float f32x4;
typedef __attribute__((ext_vector_type(4))) int int4v;

#define KSTR 36  // K_lds row stride in ushorts

__device__ __forceinline__ unsigned short f2bf_rne(float f) {
    union { float f; unsigned int u; } x;
    x.f = f;
    unsigned int u = x.u;
    return (unsigned short)((u + 0x7fffu + ((u >> 16) & 1u)) >> 16);
}
__device__ __forceinline__ unsigned short f2bf_rh(float f) {  // round-half-up
    union { float f; unsigned int u; } x;
    x.f = f;
    return (unsigned short)((x.u + 0x8000u) >> 16);
}

// Wf[pair=2s+t][lane][j] = bf16(W[i=16t+(lane&15)][crn=32s+8*(lane>>4)+j])
// plus sig f32 -> bf16 (RNE), 8 elements/thread.
__global__ __launch_bounds__(256) void prep_kernel(
        const float* __restrict__ W, const float* __restrict__ sig,
        unsigned short* __restrict__ Wf, unsigned short* __restrict__ sigbf) {
    int tid = blockIdx.x * 256 + threadIdx.x;
    if (tid < 32768) {
        int j = tid & 7;
        int l = (tid >> 3) & 63;
        int pair = tid >> 9;                    // s*2 + t
        int s = pair >> 1;
        int t = pair & 1;
        int i = 16 * t + (l & 15);
        int crn = 32 * s + 8 * (l >> 4) + j;
        Wf[tid] = f2bf_rne(W[i * 1024 + crn]);
    } else {
        int e = (tid - 32768) * 8;              // sig has 1,048,576 elements
        if (e < 8 * 4096 * 32) {
            f32x4 a = *(const f32x4*)(sig + e);
            f32x4 b = *(const f32x4*)(sig + e + 4);
            bf16x8 v;
            v[0] = (short)f2bf_rne(a[0]); v[1] = (short)f2bf_rne(a[1]);
            v[2] = (short)f2bf_rne(a[2]); v[3] = (short)f2bf_rne(a[3]);
            v[4] = (short)f2bf_rne(b[0]); v[5] = (short)f2bf_rne(b[1]);
            v[6] = (short)f2bf_rne(b[2]); v[7] = (short)f2bf_rne(b[3]);
            *(bf16x8*)(sigbf + e) = v;
        }
    }
}

__global__ __launch_bounds__(256) void fused_kernel(
        const unsigned short* __restrict__ sigbf, const int* __restrict__ pidx,
        const float* __restrict__ ck, const unsigned short* __restrict__ Wf,
        const float* __restrict__ bias, float* __restrict__ out) {
    __shared__ __align__(16) unsigned short T_lds[16 * 1032];     // 33,024 B
    __shared__ __align__(16) unsigned short K_lds[4 * 32 * KSTR]; //  9,216 B
    __shared__ __align__(16) int idx_lds[512];                    //  2,048 B
    const int tid = threadIdx.x;
    const int l = tid & 63;
    const int w = tid >> 6;          // wave 0..3
    const int m0 = blockIdx.x * 16;  // first bv of this block (same b for all 16)
    const int b = m0 >> 12;
    const int cc = l & 31;
    const int g = l >> 5;
    const unsigned short* sgb = sigbf + (size_t)b * (4096 * 32);
    unsigned short* kl = K_lds + w * 32 * KSTR;   // wave-private K tile

    // ---- issue ALL K-tile loads up front (the cold HBM stream) ----
    f32x4 kreg[4][4];
    #pragma unroll
    for (int q = 0; q < 4; ++q) {
        const f32x4* kp = (const f32x4*)(ck + (size_t)(m0 + w * 4 + q) * 1024);
        #pragma unroll
        for (int t = 0; t < 4; ++t) kreg[q][t] = kp[t * 64 + l];
        // lane holds floats (t*256 + 4l .. +3): p = t*8 + (l>>3), rn0 = 4*(l&7)
    }
    // ---- idx tile -> LDS (coalesced) ----
    {
        const int2* src = (const int2*)(pidx + (size_t)m0 * 32);
        ((int2*)idx_lds)[tid] = src[tid];
    }
    __syncthreads();

    auto issue_gathers = [&](int q, unsigned short (&gq)[16]) {
        const int base = (w * 4 + q) * 32;
        int4v ia = *(const int4v*)(idx_lds + base + 8 * g);
        int4v ib = *(const int4v*)(idx_lds + base + 8 * g + 4);
        int4v ic = *(const int4v*)(idx_lds + base + 16 + 8 * g);
        int4v id = *(const int4v*)(idx_lds + base + 16 + 8 * g + 4);
        #pragma unroll
        for (int j = 0; j < 4; ++j) {
            gq[j]      = sgb[ia[j] * 32 + cc];
            gq[4 + j]  = sgb[ib[j] * 32 + cc];
            gq[8 + j]  = sgb[ic[j] * 32 + cc];
            gq[12 + j] = sgb[id[j] * 32 + cc];
        }
    };

    auto compute_q = [&](int q, const unsigned short (&gq)[16], const f32x4 (&kq)[4]) {
        // stage K tile to LDS row-major [32p][KSTR] as bf16 (truncate)
        #pragma unroll
        for (int t = 0; t < 4; ++t) {
            union { f32x4 f; unsigned int u[4]; } x;
            x.f = kq[t];
            short4v v = { (short)(x.u[0] >> 16), (short)(x.u[1] >> 16),
                          (short)(x.u[2] >> 16), (short)(x.u[3] >> 16) };
            *(short4v*)(kl + (t * 8 + (l >> 3)) * KSTR + 4 * (l & 7)) = v;
        }
        // per-wave DS ops complete in order; compiler inserts lgkmcnt for reg deps
        f32x16 acc = {};
        #pragma unroll
        for (int half = 0; half < 2; ++half) {
            bf16x8 af, bfr;
            #pragma unroll
            for (int j = 0; j < 8; ++j) {
                af[j]  = (short)gq[half * 8 + j];
                bfr[j] = (short)kl[(half * 16 + 8 * g + j) * KSTR + cc];
            }
            acc = __builtin_amdgcn_mfma_f32_32x32x16_bf16(af, bfr, acc, 0, 0, 0);
        }
        // D map: col=cc, row=(r&3)+8*(r>>2)+4*g ; T[c][rn] bf16
        const int bvl = w * 4 + q;
        unsigned short* trow = T_lds + bvl * 1032 + cc + g * 128;
        #pragma unroll
        for (int r = 0; r < 16; ++r) {
            trow[((r & 3) + 8 * (r >> 2)) * 32] = f2bf_rh(acc[r]);
        }
    };

    unsigned short g0[16], g1[16];
    issue_gathers(0, g0);
    issue_gathers(1, g1);
    compute_q(0, g0, kreg[0]); issue_gathers(2, g0);
    compute_q(1, g1, kreg[1]); issue_gathers(3, g1);
    compute_q(2, g0, kreg[2]);
    compute_q(3, g1, kreg[3]);
    __syncthreads();

    // ---- Stage B: wave w handles k-steps s = 8w..8w+7, both i-tiles ----
    f32x4 acc0 = {}, acc1 = {};
    const int lg = l >> 4;
    const int ln = l & 15;
    #pragma unroll
    for (int si = 0; si < 8; ++si) {
        const int s = 8 * w + si;
        const bf16x8 af = *(const bf16x8*)(T_lds + ln * 1032 + s * 32 + 8 * lg);
        const bf16x8* wrow = (const bf16x8*)(Wf + (size_t)(s * 2) * 512);
        const bf16x8 b0 = wrow[l];
        const bf16x8 b1 = wrow[64 + l];
        acc0 = __builtin_amdgcn_mfma_f32_16x16x32_bf16(af, b0, acc0, 0, 0, 0);
        acc1 = __builtin_amdgcn_mfma_f32_16x16x32_bf16(af, b1, acc1, 0, 0, 0);
    }
    __syncthreads();                      // all T reads done; reuse LDS as f32 buf

    float* red = (float*)T_lds;           // 4 waves * 2 tiles * 256 f32 = 8 KB
    {
        f32x4* rp = (f32x4*)(red + w * 512);
        rp[l]      = acc0;                // [w][t=0][l][r]
        rp[64 + l] = acc1;                // [w][t=1][l][r]
    }
    __syncthreads();

    // 512 outputs: o = t*256 + l*4 + r ; D map: row(bv)=(l>>4)*4+r, col(i)=16t+(l&15)
    #pragma unroll
    for (int o0 = 0; o0 < 2; ++o0) {
        const int o = o0 * 256 + tid;
        float sum = red[o] + red[512 + o] + red[1024 + o] + red[1536 + o];
        const int t  = o >> 8;
        const int ll = (o >> 2) & 63;
        const int r  = o & 3;
        const int bv = ((ll >> 4) << 2) + r;
        const int i  = 16 * t + (ll & 15);
        sum += bias[i];
        out[(size_t)(m0 + bv) * 32 + i] = sum > 0.f ? sum : 0.f;
    }
}

extern "C" void kernel_launch(void* const* d_in, const int* in_sizes, int n_in,
                              void* d_out, int out_size, void* d_ws, size_t ws_size,
                              hipStream_t stream) {
    const float* sig  = (const float*)d_in[0];
    const int*   pidx = (const int*)d_in[1];
    const float* ck   = (const float*)d_in[2];
    const float* W    = (const float*)d_in[3];
    const float* bias = (const float*)d_in[4];
    float* out = (float*)d_out;
    unsigned short* Wf    = (unsigned short*)d_ws;       // 64 KB fragment-ordered W
    unsigned short* sigbf = Wf + 32768;                  // 2 MB bf16 signal

    prep_kernel<<<640, 256, 0, stream>>>(W, sig, Wf, sigbf);
    fused_kernel<<<2048, 256, 0, stream>>>(sigbf, pidx, ck, Wf, bias, out);
}